// Round 7
// baseline (248.023 us; speedup 1.0000x reference)
//
#include <hip/hip_runtime.h>

#define N_NODES 100000
#define N_EDGES 1600000
#define IN_C 64
#define HID_C 64
#define OUT_C 32

#define NB 391              // ceil(100000/256) dst buckets of 256 nodes
#define BSHIFT 8
#define BMASK 255
#define SEG_CAP 4864        // per-bucket capacity: mean 4096 + align pad + slack
#define EPB 6272            // 256 bin blocks (<=1 per CU) + 16-edge runs (R6)
#define BIN_BLOCKS ((N_EDGES + EPB - 1) / EPB)  // 256
#define G1_BLOCKS ((N_NODES + 63) / 64)         // 1563
#define SMASK 0x1FFFF       // 17-bit src field
#define FIXSCALE 34359738368.0f   // 2^35: count<<48 | sum(w)<<35 can't overflow

#define A2_NB 782           // agg2: ceil(100000/128) node-blocks per slice

// bf16 pack/unpack (round-to-nearest-even)
__device__ __forceinline__ unsigned int bpack(float a, float b) {
    unsigned int ua = __float_as_uint(a);
    ua += 0x7FFFu + ((ua >> 16) & 1u);
    unsigned int ub = __float_as_uint(b);
    ub += 0x7FFFu + ((ub >> 16) & 1u);
    return (ua >> 16) | (ub & 0xFFFF0000u);
}
__device__ __forceinline__ float2 bup(unsigned int v) {
    return make_float2(__uint_as_float(v << 16), __uint_as_float(v & 0xFFFF0000u));
}

// non-temporal (evict-first) load/store helpers: keep stream-once data from
// evicting gather tables out of L2.
typedef int iv4 __attribute__((ext_vector_type(4)));
typedef float fv4 __attribute__((ext_vector_type(4)));
__device__ __forceinline__ int4 ntld(const int4* p) {
    iv4 v = __builtin_nontemporal_load((const iv4*)p);
    return make_int4(v.x, v.y, v.z, v.w);
}
__device__ __forceinline__ float4 ntldf(const float4* p) {
    fv4 v = __builtin_nontemporal_load((const fv4*)p);
    return make_float4(v.x, v.y, v.z, v.w);
}
__device__ __forceinline__ void ntst(float4* p, float4 s) {
    fv4 t; t.x = s.x; t.y = s.y; t.z = s.z; t.w = s.w;
    __builtin_nontemporal_store(t, (fv4*)p);
}

// ---------------- fused pass 1: bin (blocks 0..255) + gemm1 unscaled (rest) ----------------

struct BinSh {
    int meta[EPB];      // 25.1 KB: rank within (block,bucket)
    int hist[NB];       // 1.6 KB
    int gbase[NB];      // 1.6 KB
};
struct G1Sh {
    float XsT[64][64];  // 16 KB
    float Ws[64][64];   // 16 KB
};
union FusedSh { BinSh b; G1Sh g; };  // 32 KB

__global__ void __launch_bounds__(256) fused1_kernel(
    const int* __restrict__ src, const int* __restrict__ dst,
    const float* __restrict__ w, int* __restrict__ gcnt, int2* __restrict__ seg,
    const float* __restrict__ X, const float* __restrict__ W,
    unsigned int* __restrict__ XWu) {
    __shared__ FusedSh sh;
    int tid = threadIdx.x;
    if (blockIdx.x < BIN_BLOCKS) {
        // ---- bin body ----
        for (int i = tid; i < NB; i += 256) sh.b.hist[i] = 0;
        __syncthreads();
        int e0 = blockIdx.x * EPB;
        int n = min(EPB, N_EDGES - e0);   // multiple of 4 (tail block = 640)
        const int4* dst4 = (const int4*)(dst + e0);
        int n4 = n >> 2;
        // phase 1: count + rank (dst read stays CACHED: phase 2 re-reads it).
        for (int i = tid; i < n4; i += 256) {
            int4 d = dst4[i];
            int b0 = d.x >> BSHIFT, b1 = d.y >> BSHIFT;
            int b2 = d.z >> BSHIFT, b3 = d.w >> BSHIFT;
            sh.b.meta[0 * n4 + i] = atomicAdd(&sh.b.hist[b0], 1);
            sh.b.meta[1 * n4 + i] = atomicAdd(&sh.b.hist[b1], 1);
            sh.b.meta[2 * n4 + i] = atomicAdd(&sh.b.hist[b2], 1);
            sh.b.meta[3 * n4 + i] = atomicAdd(&sh.b.hist[b3], 1);
        }
        __syncthreads();
        for (int b = tid; b < NB; b += 256) {
            int c = sh.b.hist[b];
            sh.b.gbase[b] = c ? atomicAdd(&gcnt[b], c) : 0;
        }
        __syncthreads();
        // phase 2: re-read dst (L2-hot), stream src/w (nt), scatter in runs.
        const int4* src4 = (const int4*)(src + e0);
        const float4* w4 = (const float4*)(w + e0);
        for (int i = tid; i < n4; i += 256) {
            int4 s = ntld(&src4[i]);
            int4 d = dst4[i];
            float4 ww = ntldf(&w4[i]);
#define FL_ONE(K, SS, DD, WW)                                              \
            {                                                              \
                int b = (DD) >> BSHIFT;                                    \
                int pos = sh.b.gbase[b] + sh.b.meta[K * n4 + i];           \
                if (pos < SEG_CAP)                                         \
                    seg[(size_t)b * SEG_CAP + pos] =                       \
                        make_int2((SS) | (((DD) & BMASK) << 17),           \
                                  __float_as_int(WW));                     \
            }
            FL_ONE(0, s.x, d.x, ww.x)
            FL_ONE(1, s.y, d.y, ww.y)
            FL_ONE(2, s.z, d.z, ww.z)
            FL_ONE(3, s.w, d.w, ww.w)
#undef FL_ONE
        }
    } else {
        // ---- gemm1 body: XWu = bf16(X @ W1), unscaled ----
        {
            const float4* Wv = (const float4*)W;
            float4* Wsv = (float4*)&sh.g.Ws[0][0];
            for (int i = tid; i < 1024; i += 256) Wsv[i] = Wv[i];
        }
        int row0 = (blockIdx.x - BIN_BLOCKS) * 64;
        int rmax = N_NODES - row0;
        for (int i = tid; i < 64 * 16; i += 256) {
            int r = i & 63, kq = i >> 6;  // consecutive lanes -> consecutive rows
            float4 v = (r < rmax) ? ntldf(&((const float4*)(X + (size_t)(row0 + r) * IN_C))[kq])
                                  : make_float4(0.f, 0.f, 0.f, 0.f);
            sh.g.XsT[4 * kq + 0][r] = v.x;
            sh.g.XsT[4 * kq + 1][r] = v.y;
            sh.g.XsT[4 * kq + 2][r] = v.z;
            sh.g.XsT[4 * kq + 3][r] = v.w;
        }
        __syncthreads();
        int tr = tid >> 4, tc = tid & 15;
        float acc[4][4] = {};
        float a[4], bb[4];
#pragma unroll 8
        for (int k = 0; k < 64; ++k) {
            *(float4*)a = *(const float4*)&sh.g.XsT[k][4 * tr];
            *(float4*)bb = *(const float4*)&sh.g.Ws[k][4 * tc];
#pragma unroll
            for (int i = 0; i < 4; ++i)
#pragma unroll
                for (int j = 0; j < 4; ++j) acc[i][j] += a[i] * bb[j];
        }
#pragma unroll
        for (int i = 0; i < 4; ++i) {
            int rl = 4 * tr + i;
            if (rl < rmax) {
                int row = row0 + rl;
                uint2 o;
                o.x = bpack(acc[i][0], acc[i][1]);
                o.y = bpack(acc[i][2], acc[i][3]);
                ((uint2*)XWu)[(size_t)row * 16 + tc] = o;
            }
        }
    }
}

// ---------------- pass 2: per-bucket counting sort -> runs + dinv (R6 form) ----------------

__global__ void __launch_bounds__(1024) bsort_kernel(const int* __restrict__ gcnt,
                                                     const int2* __restrict__ seg,
                                                     int2* __restrict__ seg2,
                                                     float* __restrict__ dinv,
                                                     int2* __restrict__ rowRC) {
    __shared__ unsigned long long packed[256];   // 2 KB
    __shared__ int meta[SEG_CAP];                // 19 KB: dl | rank<<8
    __shared__ int sarr[256];
    __shared__ int ofs0[256];
    int tid = threadIdx.x, b = blockIdx.x;
    int n = min(gcnt[b], SEG_CAP);
    const int2* sp = seg + (size_t)b * SEG_CAP;
    if (tid < 256) packed[tid] = 0ULL;
    __syncthreads();
    for (int i = tid; i < n; i += 1024) {
        int2 r = sp[i];
        int dl = (r.x >> 17) & BMASK;
        unsigned long long fixw =
            (unsigned long long)(__int_as_float(r.y) * FIXSCALE);
        unsigned long long old = atomicAdd(&packed[dl], (1ULL << 48) | fixw);
        meta[i] = dl | ((int)(old >> 48) << 8);
    }
    __syncthreads();
    int myc = 0, padc = 0;
    if (tid < 256) {
        unsigned long long p = packed[tid];
        myc = (int)(p >> 48);
        float degw = (float)((double)(p & ((1ULL << 48) - 1)) * (1.0 / (double)FIXSCALE));
        float dv = rsqrtf(1.0f + degw);  // self-loop w=1
        int node = (b << BSHIFT) + tid;
        if (node < N_NODES) dinv[node] = dv;
        padc = (myc + 1) & ~1;  // even-align runs for int4 loads
        sarr[tid] = padc;
    }
    __syncthreads();
    for (int off = 1; off < 256; off <<= 1) {
        int tmp = 0;
        if (tid < 256 && tid >= off) tmp = sarr[tid - off];
        __syncthreads();
        if (tid < 256) sarr[tid] += tmp;
        __syncthreads();
    }
    if (tid < 256) {
        int excl = sarr[tid] - padc;
        int node = (b << BSHIFT) + tid;
        if (node < N_NODES) rowRC[node] = make_int2(b * SEG_CAP + excl, myc);
        ofs0[tid] = excl;
    }
    __syncthreads();
    int2* op = seg2 + (size_t)b * SEG_CAP;
    for (int i = tid; i < n; i += 1024) {
        int2 r = sp[i];                       // re-read, L2-hot
        int m = meta[i];
        int dl = m & BMASK, rank = m >> 8;
        op[ofs0[dl] + rank] = r;
    }
}

// ---------------- agg layer 1 + GEMM2 fused ----------------
// As R6 (uint4 gathers, dinv[s] folded per edge) + nt record loads; the
// epilogue now writes HWs SLICE-MAJOR: HWs[slice][node][16ch] (2 x 3.2 MB),
// so agg2's XCD-pinned slices are line-pure and L2-resident.

__global__ void __launch_bounds__(256) agg1_kernel(const int2* __restrict__ rowRC,
                                                   const int2* __restrict__ seg2,
                                                   const unsigned int* __restrict__ XWs,
                                                   const float* __restrict__ dinv,
                                                   const float* __restrict__ b1,
                                                   const float* __restrict__ W2,
                                                   unsigned int* __restrict__ HWs) {
    __shared__ float Hs[32][68];    // 8.5 KB (+4 pad)
    __shared__ float Ws2[64][32];   // 8 KB
    int tid = threadIdx.x;
    {   // stage W2 while gathers are in flight
        const float4* Wv = (const float4*)W2;
        float4* Wsv = (float4*)&Ws2[0][0];
        for (int i = tid; i < 512; i += 256) Wsv[i] = Wv[i];
    }
    int l8 = tid & 7;                        // channel-octet lane 0..7
    int nl = tid >> 3;                       // node-local 0..31
    int d = blockIdx.x * 32 + nl;            // always < N_NODES (3125*32)
    const uint4* XW4 = (const uint4*)XWs;    // row = 8 uint4 (128 B)
    float did = dinv[d];
    float selfc = did * did;                 // self-loop: dinv[d] * 1 * dinv[d]
    float4 bv0 = ((const float4*)b1)[2 * l8];
    float4 bv1 = ((const float4*)b1)[2 * l8 + 1];
    uint4 sv = XW4[(size_t)d * 8 + l8];
    float2 v;
    float a0, a1, a2, a3, a4, a5, a6, a7;
    v = bup(sv.x); a0 = bv0.x + selfc * v.x; a1 = bv0.y + selfc * v.y;
    v = bup(sv.y); a2 = bv0.z + selfc * v.x; a3 = bv0.w + selfc * v.y;
    v = bup(sv.z); a4 = bv1.x + selfc * v.x; a5 = bv1.y + selfc * v.y;
    v = bup(sv.w); a6 = bv1.z + selfc * v.x; a7 = bv1.w + selfc * v.y;
    int2 rc = rowRC[d];
    int nc = rc.y;
    const int2* sp = seg2 + rc.x;
    const int4* sp4 = (const int4*)sp;
    int e = 0;
#define ACC1(R, C)                                                         \
    v = bup(R.x); a0 += (C) * v.x; a1 += (C) * v.y;                        \
    v = bup(R.y); a2 += (C) * v.x; a3 += (C) * v.y;                        \
    v = bup(R.z); a4 += (C) * v.x; a5 += (C) * v.y;                        \
    v = bup(R.w); a6 += (C) * v.x; a7 += (C) * v.y;
    for (; e + 8 <= nc; e += 8) {
        int4 q0 = ntld(&sp4[(e >> 1) + 0]), q1 = ntld(&sp4[(e >> 1) + 1]);
        int4 q2 = ntld(&sp4[(e >> 1) + 2]), q3 = ntld(&sp4[(e >> 1) + 3]);
        int s0 = q0.x & SMASK, s1 = q0.z & SMASK, s2 = q1.x & SMASK, s3 = q1.z & SMASK;
        int s4 = q2.x & SMASK, s5 = q2.z & SMASK, s6 = q3.x & SMASK, s7 = q3.z & SMASK;
        float ds0 = dinv[s0], ds1 = dinv[s1], ds2 = dinv[s2], ds3 = dinv[s3];
        float ds4 = dinv[s4], ds5 = dinv[s5], ds6 = dinv[s6], ds7 = dinv[s7];
        uint4 r0 = XW4[(size_t)s0 * 8 + l8];
        uint4 r1 = XW4[(size_t)s1 * 8 + l8];
        uint4 r2 = XW4[(size_t)s2 * 8 + l8];
        uint4 r3 = XW4[(size_t)s3 * 8 + l8];
        uint4 r4 = XW4[(size_t)s4 * 8 + l8];
        uint4 r5 = XW4[(size_t)s5 * 8 + l8];
        uint4 r6 = XW4[(size_t)s6 * 8 + l8];
        uint4 r7 = XW4[(size_t)s7 * 8 + l8];
        float c0 = __int_as_float(q0.y) * did * ds0, c1 = __int_as_float(q0.w) * did * ds1;
        float c2 = __int_as_float(q1.y) * did * ds2, c3 = __int_as_float(q1.w) * did * ds3;
        float c4 = __int_as_float(q2.y) * did * ds4, c5 = __int_as_float(q2.w) * did * ds5;
        float c6 = __int_as_float(q3.y) * did * ds6, c7 = __int_as_float(q3.w) * did * ds7;
        ACC1(r0, c0) ACC1(r1, c1) ACC1(r2, c2) ACC1(r3, c3)
        ACC1(r4, c4) ACC1(r5, c5) ACC1(r6, c6) ACC1(r7, c7)
    }
    for (; e + 2 <= nc; e += 2) {
        int4 q = sp4[e >> 1];
        int s0 = q.x & SMASK, s1 = q.z & SMASK;
        float ds0 = dinv[s0], ds1 = dinv[s1];
        uint4 r0 = XW4[(size_t)s0 * 8 + l8];
        uint4 r1 = XW4[(size_t)s1 * 8 + l8];
        float c0 = __int_as_float(q.y) * did * ds0, c1 = __int_as_float(q.w) * did * ds1;
        ACC1(r0, c0) ACC1(r1, c1)
    }
    if (e < nc) {
        int2 p = sp[e];
        int s = p.x & SMASK;
        float c = __int_as_float(p.y) * did * dinv[s];
        uint4 r = XW4[(size_t)s * 8 + l8];
        ACC1(r, c)
    }
#undef ACC1
    // ---- ReLU + stage H tile (thread (nl,l8) holds ch 8*l8..8*l8+7 of node nl) ----
    *(float4*)&Hs[nl][8 * l8] = make_float4(fmaxf(a0, 0.f), fmaxf(a1, 0.f),
                                            fmaxf(a2, 0.f), fmaxf(a3, 0.f));
    *(float4*)&Hs[nl][8 * l8 + 4] = make_float4(fmaxf(a4, 0.f), fmaxf(a5, 0.f),
                                                fmaxf(a6, 0.f), fmaxf(a7, 0.f));
    __syncthreads();
    // ---- 32x64 @ 64x32 epilogue: HWs = bf16(H @ W2), UNSCALED, SLICE-MAJOR ----
    int nl2 = tid >> 3, cg = tid & 7;        // cg: 4-ch group; slice = cg>>2
    int d2 = blockIdx.x * 32 + nl2;
    float o0 = 0.f, o1 = 0.f, o2 = 0.f, o3 = 0.f;
#pragma unroll
    for (int k = 0; k < 64; ++k) {
        float hk = Hs[nl2][k];                      // broadcast within 8-lane group
        float4 wv = *(const float4*)&Ws2[k][4 * cg];
        o0 += hk * wv.x; o1 += hk * wv.y; o2 += hk * wv.z; o3 += hk * wv.w;
    }
    uint2 o;
    o.x = bpack(o0, o1);
    o.y = bpack(o2, o3);
    // slice-major: HWs[slice][node][4 x uint2]; slice stride = 100000*4 uint2
    ((uint2*)HWs)[(size_t)(cg >> 2) * 400000 + (size_t)d2 * 4 + (cg & 3)] = o;
}

// ---------------- agg layer 2: XCD-pinned channel slices (R7) ----------------
// slice = (bid%8)>>2: XCDs 0-3 own slice 0 (ch 0-15), XCDs 4-7 slice 1.
// Each slice table = 3.2 MB slice-major -> L2-RESIDENT per XCD; gathers become
// L2 hits. Records are read by both slices (nt-hinted, streaming). 128
// nodes/block, 2 lanes/node x uint4.

__global__ void __launch_bounds__(256) agg2_kernel(const int2* __restrict__ rowRC,
                                                   const int2* __restrict__ seg2,
                                                   const unsigned int* __restrict__ HWs,
                                                   const float* __restrict__ dinv,
                                                   const float* __restrict__ b2,
                                                   float* __restrict__ out) {
    int bid = blockIdx.x;
    int slice = (bid & 7) >> 2;              // XCD 0-3 -> 0, XCD 4-7 -> 1
    int nb = ((bid >> 3) << 2) | (bid & 3);  // node-block within slice
    if (nb >= A2_NB) return;
    int l2 = threadIdx.x & 1;                // 16-B lane within 32-B slice row
    int d = nb * 128 + (threadIdx.x >> 1);
    if (d >= N_NODES) return;
    const uint4* T = (const uint4*)HWs + (size_t)slice * 200000;  // slice base
    float did = dinv[d];
    float selfc = did * did;
    float4 bv0 = ((const float4*)b2)[slice * 4 + l2 * 2];
    float4 bv1 = ((const float4*)b2)[slice * 4 + l2 * 2 + 1];
    uint4 sv = T[(size_t)d * 2 + l2];
    float2 v;
    float a0, a1, a2, a3, a4, a5, a6, a7;
    v = bup(sv.x); a0 = bv0.x + selfc * v.x; a1 = bv0.y + selfc * v.y;
    v = bup(sv.y); a2 = bv0.z + selfc * v.x; a3 = bv0.w + selfc * v.y;
    v = bup(sv.z); a4 = bv1.x + selfc * v.x; a5 = bv1.y + selfc * v.y;
    v = bup(sv.w); a6 = bv1.z + selfc * v.x; a7 = bv1.w + selfc * v.y;
    int2 rc = rowRC[d];
    int nc = rc.y;
    const int2* sp = seg2 + rc.x;
    const int4* sp4 = (const int4*)sp;
    int e = 0;
#define ACC2(R, C)                                                         \
    v = bup(R.x); a0 += (C) * v.x; a1 += (C) * v.y;                        \
    v = bup(R.y); a2 += (C) * v.x; a3 += (C) * v.y;                        \
    v = bup(R.z); a4 += (C) * v.x; a5 += (C) * v.y;                        \
    v = bup(R.w); a6 += (C) * v.x; a7 += (C) * v.y;
    for (; e + 8 <= nc; e += 8) {
        int4 q0 = ntld(&sp4[(e >> 1) + 0]), q1 = ntld(&sp4[(e >> 1) + 1]);
        int4 q2 = ntld(&sp4[(e >> 1) + 2]), q3 = ntld(&sp4[(e >> 1) + 3]);
        int s0 = q0.x & SMASK, s1 = q0.z & SMASK, s2 = q1.x & SMASK, s3 = q1.z & SMASK;
        int s4 = q2.x & SMASK, s5 = q2.z & SMASK, s6 = q3.x & SMASK, s7 = q3.z & SMASK;
        float ds0 = dinv[s0], ds1 = dinv[s1], ds2 = dinv[s2], ds3 = dinv[s3];
        float ds4 = dinv[s4], ds5 = dinv[s5], ds6 = dinv[s6], ds7 = dinv[s7];
        uint4 r0 = T[(size_t)s0 * 2 + l2];
        uint4 r1 = T[(size_t)s1 * 2 + l2];
        uint4 r2 = T[(size_t)s2 * 2 + l2];
        uint4 r3 = T[(size_t)s3 * 2 + l2];
        uint4 r4 = T[(size_t)s4 * 2 + l2];
        uint4 r5 = T[(size_t)s5 * 2 + l2];
        uint4 r6 = T[(size_t)s6 * 2 + l2];
        uint4 r7 = T[(size_t)s7 * 2 + l2];
        float c0 = __int_as_float(q0.y) * did * ds0, c1 = __int_as_float(q0.w) * did * ds1;
        float c2 = __int_as_float(q1.y) * did * ds2, c3 = __int_as_float(q1.w) * did * ds3;
        float c4 = __int_as_float(q2.y) * did * ds4, c5 = __int_as_float(q2.w) * did * ds5;
        float c6 = __int_as_float(q3.y) * did * ds6, c7 = __int_as_float(q3.w) * did * ds7;
        ACC2(r0, c0) ACC2(r1, c1) ACC2(r2, c2) ACC2(r3, c3)
        ACC2(r4, c4) ACC2(r5, c5) ACC2(r6, c6) ACC2(r7, c7)
    }
    for (; e + 2 <= nc; e += 2) {
        int4 q = sp4[e >> 1];
        int s0 = q.x & SMASK, s1 = q.z & SMASK;
        float ds0 = dinv[s0], ds1 = dinv[s1];
        uint4 r0 = T[(size_t)s0 * 2 + l2];
        uint4 r1 = T[(size_t)s1 * 2 + l2];
        float c0 = __int_as_float(q.y) * did * ds0, c1 = __int_as_float(q.w) * did * ds1;
        ACC2(r0, c0) ACC2(r1, c1)
    }
    if (e < nc) {
        int2 p = sp[e];
        int s = p.x & SMASK;
        float c = __int_as_float(p.y) * did * dinv[s];
        uint4 r = T[(size_t)s * 2 + l2];
        ACC2(r, c)
    }
#undef ACC2
    float4* o4 = (float4*)out + (size_t)d * 8 + slice * 4 + l2 * 2;
    ntst(o4, make_float4(a0, a1, a2, a3));
    ntst(o4 + 1, make_float4(a4, a5, a6, a7));
}

// ---------------- launch ----------------

extern "C" void kernel_launch(void* const* d_in, const int* in_sizes, int n_in,
                              void* d_out, int out_size, void* d_ws, size_t ws_size,
                              hipStream_t stream) {
    const float* x = (const float*)d_in[0];
    const int* edge_index = (const int*)d_in[1];
    const float* ew = (const float*)d_in[2];
    const float* W1 = (const float*)d_in[3];
    const float* b1 = (const float*)d_in[4];
    const float* W2 = (const float*)d_in[5];
    const float* b2 = (const float*)d_in[6];
    float* out = (float*)d_out;

    const int* src = edge_index;
    const int* dst = edge_index + N_EDGES;

    char* ws = (char*)d_ws;
    size_t off = 0;
    auto carve = [&](size_t bytes) -> void* {
        void* p = ws + off;
        off += (bytes + 255) & ~(size_t)255;
        return p;
    };

    int* gcnt = (int*)carve(NB * 4);
    float* dinv = (float*)carve((size_t)N_NODES * 4);
    int2* rowRC = (int2*)carve((size_t)N_NODES * 8);
    int2* seg = (int2*)carve((size_t)NB * SEG_CAP * 8);          // 15.2 MB
    int2* seg2 = (int2*)carve((size_t)NB * SEG_CAP * 8);         // 15.2 MB
    unsigned int* XWs = (unsigned int*)carve((size_t)N_NODES * 32 * 4);  // 12.8 MB bf16x2
    unsigned int* HWs = (unsigned int*)carve((size_t)N_NODES * 16 * 4);  // 6.4 MB slice-major

    hipMemsetAsync(gcnt, 0, NB * 4, stream);
    fused1_kernel<<<BIN_BLOCKS + G1_BLOCKS, 256, 0, stream>>>(src, dst, ew, gcnt, seg,
                                                              x, W1, XWs);
    bsort_kernel<<<NB, 1024, 0, stream>>>(gcnt, seg, seg2, dinv, rowRC);
    agg1_kernel<<<N_NODES / 32, 256, 0, stream>>>(rowRC, seg2, XWs, dinv, b1, W2, HWs);
    agg2_kernel<<<1568, 256, 0, stream>>>(rowRC, seg2, HWs, dinv, b2, out);
}

// Round 8
// 209.720 us; speedup vs baseline: 1.1826x; 1.1826x over previous
//
#include <hip/hip_runtime.h>

#define N_NODES 100000
#define N_EDGES 1600000
#define IN_C 64
#define HID_C 64
#define OUT_C 32

#define NB 391              // ceil(100000/256) dst buckets of 256 nodes
#define BSHIFT 8
#define BMASK 255
#define SEG_CAP 4864        // per-bucket capacity: mean 4096 + align pad + slack
#define EPB 6272            // 256 bin blocks (<=1 per CU) + 16-edge runs (R6)
#define BIN_BLOCKS ((N_EDGES + EPB - 1) / EPB)  // 256
#define G1_BLOCKS ((N_NODES + 127) / 128)       // 782 (128-row tiles, R8)
#define SMASK 0x1FFFF       // 17-bit src field
#define FIXSCALE 34359738368.0f   // 2^35: count<<48 | sum(w)<<35 can't overflow

// bf16 pack/unpack (round-to-nearest-even)
__device__ __forceinline__ unsigned int bpack(float a, float b) {
    unsigned int ua = __float_as_uint(a);
    ua += 0x7FFFu + ((ua >> 16) & 1u);
    unsigned int ub = __float_as_uint(b);
    ub += 0x7FFFu + ((ub >> 16) & 1u);
    return (ua >> 16) | (ub & 0xFFFF0000u);
}
__device__ __forceinline__ float2 bup(unsigned int v) {
    return make_float2(__uint_as_float(v << 16), __uint_as_float(v & 0xFFFF0000u));
}

// ---------------- fused pass 1: bin (blocks 0..255) + gemm1 unscaled (rest) ----------------
// R8: 512-thread blocks. Bin gets 8 waves (2x latency hiding in the bin-alone
// tail; R6 measured occupancy 29%, VALUBusy 21% with 4-wave bin blocks).
// Gemm1 does 128-row tiles. Inner micro-kernels byte-identical to R6.

struct BinSh {
    int meta[EPB];      // 25.1 KB: rank within (block,bucket)
    int hist[NB];       // 1.6 KB
    int gbase[NB];      // 1.6 KB
};
struct G1Sh {
    float XsT[64][128]; // 32 KB
    float Ws[64][64];   // 16 KB
};
union FusedSh { BinSh b; G1Sh g; };  // 48 KB -> 3 blocks/CU (24 waves)

__global__ void __launch_bounds__(512) fused1_kernel(
    const int* __restrict__ src, const int* __restrict__ dst,
    const float* __restrict__ w, int* __restrict__ gcnt, int2* __restrict__ seg,
    const float* __restrict__ X, const float* __restrict__ W,
    unsigned int* __restrict__ XWu) {
    __shared__ FusedSh sh;
    int tid = threadIdx.x;
    if (blockIdx.x < BIN_BLOCKS) {
        // ---- bin body ----
        for (int i = tid; i < NB; i += 512) sh.b.hist[i] = 0;
        __syncthreads();
        int e0 = blockIdx.x * EPB;
        int n = min(EPB, N_EDGES - e0);   // multiple of 4 (tail block = 640)
        const int4* dst4 = (const int4*)(dst + e0);
        int n4 = n >> 2;
        // phase 1: count + rank.  meta slot transposed (K*n4+i): stride-1 per lane.
        for (int i = tid; i < n4; i += 512) {
            int4 d = dst4[i];
            int b0 = d.x >> BSHIFT, b1 = d.y >> BSHIFT;
            int b2 = d.z >> BSHIFT, b3 = d.w >> BSHIFT;
            sh.b.meta[0 * n4 + i] = atomicAdd(&sh.b.hist[b0], 1);
            sh.b.meta[1 * n4 + i] = atomicAdd(&sh.b.hist[b1], 1);
            sh.b.meta[2 * n4 + i] = atomicAdd(&sh.b.hist[b2], 1);
            sh.b.meta[3 * n4 + i] = atomicAdd(&sh.b.hist[b3], 1);
        }
        __syncthreads();
        for (int b = tid; b < NB; b += 512) {
            int c = sh.b.hist[b];
            sh.b.gbase[b] = c ? atomicAdd(&gcnt[b], c) : 0;
        }
        __syncthreads();
        // phase 2: re-read edges (L2-hot), recompute record, scatter in runs.
        const int4* src4 = (const int4*)(src + e0);
        const float4* w4 = (const float4*)(w + e0);
        for (int i = tid; i < n4; i += 512) {
            int4 s = src4[i];
            int4 d = dst4[i];
            float4 ww = w4[i];
#define FL_ONE(K, SS, DD, WW)                                              \
            {                                                              \
                int b = (DD) >> BSHIFT;                                    \
                int pos = sh.b.gbase[b] + sh.b.meta[K * n4 + i];           \
                if (pos < SEG_CAP)                                         \
                    seg[(size_t)b * SEG_CAP + pos] =                       \
                        make_int2((SS) | (((DD) & BMASK) << 17),           \
                                  __float_as_int(WW));                     \
            }
            FL_ONE(0, s.x, d.x, ww.x)
            FL_ONE(1, s.y, d.y, ww.y)
            FL_ONE(2, s.z, d.z, ww.z)
            FL_ONE(3, s.w, d.w, ww.w)
#undef FL_ONE
        }
    } else {
        // ---- gemm1 body: XWu = bf16(X @ W1), unscaled; 128-row tile ----
        {
            const float4* Wv = (const float4*)W;
            float4* Wsv = (float4*)&sh.g.Ws[0][0];
            for (int i = tid; i < 1024; i += 512) Wsv[i] = Wv[i];
        }
        int row0 = (blockIdx.x - BIN_BLOCKS) * 128;
        int rmax = N_NODES - row0;
        for (int i = tid; i < 128 * 16; i += 512) {
            int r = i & 127, kq = i >> 7;  // consecutive lanes -> consecutive rows
            float4 v = (r < rmax) ? ((const float4*)(X + (size_t)(row0 + r) * IN_C))[kq]
                                  : make_float4(0.f, 0.f, 0.f, 0.f);
            sh.g.XsT[4 * kq + 0][r] = v.x;
            sh.g.XsT[4 * kq + 1][r] = v.y;
            sh.g.XsT[4 * kq + 2][r] = v.z;
            sh.g.XsT[4 * kq + 3][r] = v.w;
        }
        __syncthreads();
        int tr = tid >> 4, tc = tid & 15;    // tr 0..31 (4 rows each), tc 0..15
        float acc[4][4] = {};
        float a[4], bb[4];
#pragma unroll 8
        for (int k = 0; k < 64; ++k) {
            *(float4*)a = *(const float4*)&sh.g.XsT[k][4 * tr];
            *(float4*)bb = *(const float4*)&sh.g.Ws[k][4 * tc];
#pragma unroll
            for (int i = 0; i < 4; ++i)
#pragma unroll
                for (int j = 0; j < 4; ++j) acc[i][j] += a[i] * bb[j];
        }
#pragma unroll
        for (int i = 0; i < 4; ++i) {
            int rl = 4 * tr + i;
            if (rl < rmax) {
                int row = row0 + rl;
                uint2 o;
                o.x = bpack(acc[i][0], acc[i][1]);
                o.y = bpack(acc[i][2], acc[i][3]);
                ((uint2*)XWu)[(size_t)row * 16 + tc] = o;
            }
        }
    }
}

// ---------------- pass 2: per-bucket counting sort -> runs + dinv (R6 form) ----------------

__global__ void __launch_bounds__(1024) bsort_kernel(const int* __restrict__ gcnt,
                                                     const int2* __restrict__ seg,
                                                     int2* __restrict__ seg2,
                                                     float* __restrict__ dinv,
                                                     int2* __restrict__ rowRC) {
    __shared__ unsigned long long packed[256];   // 2 KB
    __shared__ int meta[SEG_CAP];                // 19 KB: dl | rank<<8
    __shared__ int sarr[256];
    __shared__ int ofs0[256];
    int tid = threadIdx.x, b = blockIdx.x;
    int n = min(gcnt[b], SEG_CAP);
    const int2* sp = seg + (size_t)b * SEG_CAP;
    if (tid < 256) packed[tid] = 0ULL;
    __syncthreads();
    for (int i = tid; i < n; i += 1024) {
        int2 r = sp[i];
        int dl = (r.x >> 17) & BMASK;
        unsigned long long fixw =
            (unsigned long long)(__int_as_float(r.y) * FIXSCALE);
        unsigned long long old = atomicAdd(&packed[dl], (1ULL << 48) | fixw);
        meta[i] = dl | ((int)(old >> 48) << 8);
    }
    __syncthreads();
    int myc = 0, padc = 0;
    if (tid < 256) {
        unsigned long long p = packed[tid];
        myc = (int)(p >> 48);
        float degw = (float)((double)(p & ((1ULL << 48) - 1)) * (1.0 / (double)FIXSCALE));
        float dv = rsqrtf(1.0f + degw);  // self-loop w=1
        int node = (b << BSHIFT) + tid;
        if (node < N_NODES) dinv[node] = dv;
        padc = (myc + 1) & ~1;  // even-align runs for int4 loads
        sarr[tid] = padc;
    }
    __syncthreads();
    for (int off = 1; off < 256; off <<= 1) {
        int tmp = 0;
        if (tid < 256 && tid >= off) tmp = sarr[tid - off];
        __syncthreads();
        if (tid < 256) sarr[tid] += tmp;
        __syncthreads();
    }
    if (tid < 256) {
        int excl = sarr[tid] - padc;
        int node = (b << BSHIFT) + tid;
        if (node < N_NODES) rowRC[node] = make_int2(b * SEG_CAP + excl, myc);
        ofs0[tid] = excl;
    }
    __syncthreads();
    int2* op = seg2 + (size_t)b * SEG_CAP;
    for (int i = tid; i < n; i += 1024) {
        int2 r = sp[i];                       // re-read, L2-hot
        int m = meta[i];
        int dl = m & BMASK, rank = m >> 8;
        op[ofs0[dl] + rank] = r;
    }
}

// ---------------- agg layer 1 + GEMM2 fused (R6-proven form) ----------------

__global__ void __launch_bounds__(256) agg1_kernel(const int2* __restrict__ rowRC,
                                                   const int2* __restrict__ seg2,
                                                   const unsigned int* __restrict__ XWs,
                                                   const float* __restrict__ dinv,
                                                   const float* __restrict__ b1,
                                                   const float* __restrict__ W2,
                                                   unsigned int* __restrict__ HWs) {
    __shared__ float Hs[32][68];    // 8.5 KB (+4 pad)
    __shared__ float Ws2[64][32];   // 8 KB
    int tid = threadIdx.x;
    {   // stage W2 while gathers are in flight
        const float4* Wv = (const float4*)W2;
        float4* Wsv = (float4*)&Ws2[0][0];
        for (int i = tid; i < 512; i += 256) Wsv[i] = Wv[i];
    }
    int l8 = tid & 7;                        // channel-octet lane 0..7
    int nl = tid >> 3;                       // node-local 0..31
    int d = blockIdx.x * 32 + nl;            // always < N_NODES (3125*32)
    const uint4* XW4 = (const uint4*)XWs;    // row = 8 uint4 (128 B)
    float did = dinv[d];
    float selfc = did * did;                 // self-loop: dinv[d] * 1 * dinv[d]
    float4 bv0 = ((const float4*)b1)[2 * l8];
    float4 bv1 = ((const float4*)b1)[2 * l8 + 1];
    uint4 sv = XW4[(size_t)d * 8 + l8];
    float2 v;
    float a0, a1, a2, a3, a4, a5, a6, a7;
    v = bup(sv.x); a0 = bv0.x + selfc * v.x; a1 = bv0.y + selfc * v.y;
    v = bup(sv.y); a2 = bv0.z + selfc * v.x; a3 = bv0.w + selfc * v.y;
    v = bup(sv.z); a4 = bv1.x + selfc * v.x; a5 = bv1.y + selfc * v.y;
    v = bup(sv.w); a6 = bv1.z + selfc * v.x; a7 = bv1.w + selfc * v.y;
    int2 rc = rowRC[d];
    int nc = rc.y;
    const int2* sp = seg2 + rc.x;
    const int4* sp4 = (const int4*)sp;
    int e = 0;
#define ACC1(R, C)                                                         \
    v = bup(R.x); a0 += (C) * v.x; a1 += (C) * v.y;                        \
    v = bup(R.y); a2 += (C) * v.x; a3 += (C) * v.y;                        \
    v = bup(R.z); a4 += (C) * v.x; a5 += (C) * v.y;                        \
    v = bup(R.w); a6 += (C) * v.x; a7 += (C) * v.y;
    for (; e + 8 <= nc; e += 8) {
        int4 q0 = sp4[(e >> 1) + 0], q1 = sp4[(e >> 1) + 1];
        int4 q2 = sp4[(e >> 1) + 2], q3 = sp4[(e >> 1) + 3];
        int s0 = q0.x & SMASK, s1 = q0.z & SMASK, s2 = q1.x & SMASK, s3 = q1.z & SMASK;
        int s4 = q2.x & SMASK, s5 = q2.z & SMASK, s6 = q3.x & SMASK, s7 = q3.z & SMASK;
        float ds0 = dinv[s0], ds1 = dinv[s1], ds2 = dinv[s2], ds3 = dinv[s3];
        float ds4 = dinv[s4], ds5 = dinv[s5], ds6 = dinv[s6], ds7 = dinv[s7];
        uint4 r0 = XW4[(size_t)s0 * 8 + l8];
        uint4 r1 = XW4[(size_t)s1 * 8 + l8];
        uint4 r2 = XW4[(size_t)s2 * 8 + l8];
        uint4 r3 = XW4[(size_t)s3 * 8 + l8];
        uint4 r4 = XW4[(size_t)s4 * 8 + l8];
        uint4 r5 = XW4[(size_t)s5 * 8 + l8];
        uint4 r6 = XW4[(size_t)s6 * 8 + l8];
        uint4 r7 = XW4[(size_t)s7 * 8 + l8];
        float c0 = __int_as_float(q0.y) * did * ds0, c1 = __int_as_float(q0.w) * did * ds1;
        float c2 = __int_as_float(q1.y) * did * ds2, c3 = __int_as_float(q1.w) * did * ds3;
        float c4 = __int_as_float(q2.y) * did * ds4, c5 = __int_as_float(q2.w) * did * ds5;
        float c6 = __int_as_float(q3.y) * did * ds6, c7 = __int_as_float(q3.w) * did * ds7;
        ACC1(r0, c0) ACC1(r1, c1) ACC1(r2, c2) ACC1(r3, c3)
        ACC1(r4, c4) ACC1(r5, c5) ACC1(r6, c6) ACC1(r7, c7)
    }
    for (; e + 2 <= nc; e += 2) {
        int4 q = sp4[e >> 1];
        int s0 = q.x & SMASK, s1 = q.z & SMASK;
        float ds0 = dinv[s0], ds1 = dinv[s1];
        uint4 r0 = XW4[(size_t)s0 * 8 + l8];
        uint4 r1 = XW4[(size_t)s1 * 8 + l8];
        float c0 = __int_as_float(q.y) * did * ds0, c1 = __int_as_float(q.w) * did * ds1;
        ACC1(r0, c0) ACC1(r1, c1)
    }
    if (e < nc) {
        int2 p = sp[e];
        int s = p.x & SMASK;
        float c = __int_as_float(p.y) * did * dinv[s];
        uint4 r = XW4[(size_t)s * 8 + l8];
        ACC1(r, c)
    }
#undef ACC1
    // ---- ReLU + stage H tile (thread (nl,l8) holds ch 8*l8..8*l8+7 of node nl) ----
    *(float4*)&Hs[nl][8 * l8] = make_float4(fmaxf(a0, 0.f), fmaxf(a1, 0.f),
                                            fmaxf(a2, 0.f), fmaxf(a3, 0.f));
    *(float4*)&Hs[nl][8 * l8 + 4] = make_float4(fmaxf(a4, 0.f), fmaxf(a5, 0.f),
                                                fmaxf(a6, 0.f), fmaxf(a7, 0.f));
    __syncthreads();
    // ---- 32x64 @ 64x32 epilogue: HWs = bf16(H @ W2), UNSCALED (agg2 applies dinv) ----
    int nl2 = tid >> 3, cg = tid & 7;
    int d2 = blockIdx.x * 32 + nl2;
    float o0 = 0.f, o1 = 0.f, o2 = 0.f, o3 = 0.f;
#pragma unroll
    for (int k = 0; k < 64; ++k) {
        float hk = Hs[nl2][k];                      // broadcast within 8-lane group
        float4 wv = *(const float4*)&Ws2[k][4 * cg];
        o0 += hk * wv.x; o1 += hk * wv.y; o2 += hk * wv.z; o3 += hk * wv.w;
    }
    uint2 o;
    o.x = bpack(o0, o1);
    o.y = bpack(o2, o3);
    ((uint2*)HWs)[(size_t)d2 * 8 + cg] = o;   // row = 8 uint2 (64 B)
}

// ---------------- agg layer 2: 16 nodes/wave, uint4/lane, dinv[s] per edge (R6 form) ------

__global__ void __launch_bounds__(256) agg2_kernel(const int2* __restrict__ rowRC,
                                                   const int2* __restrict__ seg2,
                                                   const unsigned int* __restrict__ HWs,
                                                   const float* __restrict__ dinv,
                                                   const float* __restrict__ b2,
                                                   float* __restrict__ out) {
    int l4 = threadIdx.x & 3;                // channel-octet lane 0..3
    int d = blockIdx.x * 64 + (threadIdx.x >> 2);
    if (d >= N_NODES) return;
    const uint4* HW4 = (const uint4*)HWs;    // row = 4 uint4 (64 B)
    float did = dinv[d];
    float selfc = did * did;
    float4 bv0 = ((const float4*)b2)[2 * l4];
    float4 bv1 = ((const float4*)b2)[2 * l4 + 1];
    uint4 sv = HW4[(size_t)d * 4 + l4];
    float2 v;
    float a0, a1, a2, a3, a4, a5, a6, a7;
    v = bup(sv.x); a0 = bv0.x + selfc * v.x; a1 = bv0.y + selfc * v.y;
    v = bup(sv.y); a2 = bv0.z + selfc * v.x; a3 = bv0.w + selfc * v.y;
    v = bup(sv.z); a4 = bv1.x + selfc * v.x; a5 = bv1.y + selfc * v.y;
    v = bup(sv.w); a6 = bv1.z + selfc * v.x; a7 = bv1.w + selfc * v.y;
    int2 rc = rowRC[d];
    int nc = rc.y;
    const int2* sp = seg2 + rc.x;
    const int4* sp4 = (const int4*)sp;
    int e = 0;
#define ACC2(R, C)                                                         \
    v = bup(R.x); a0 += (C) * v.x; a1 += (C) * v.y;                        \
    v = bup(R.y); a2 += (C) * v.x; a3 += (C) * v.y;                        \
    v = bup(R.z); a4 += (C) * v.x; a5 += (C) * v.y;                        \
    v = bup(R.w); a6 += (C) * v.x; a7 += (C) * v.y;
    for (; e + 8 <= nc; e += 8) {
        int4 q0 = sp4[(e >> 1) + 0], q1 = sp4[(e >> 1) + 1];
        int4 q2 = sp4[(e >> 1) + 2], q3 = sp4[(e >> 1) + 3];
        int s0 = q0.x & SMASK, s1 = q0.z & SMASK, s2 = q1.x & SMASK, s3 = q1.z & SMASK;
        int s4 = q2.x & SMASK, s5 = q2.z & SMASK, s6 = q3.x & SMASK, s7 = q3.z & SMASK;
        float ds0 = dinv[s0], ds1 = dinv[s1], ds2 = dinv[s2], ds3 = dinv[s3];
        float ds4 = dinv[s4], ds5 = dinv[s5], ds6 = dinv[s6], ds7 = dinv[s7];
        uint4 r0 = HW4[(size_t)s0 * 4 + l4];
        uint4 r1 = HW4[(size_t)s1 * 4 + l4];
        uint4 r2 = HW4[(size_t)s2 * 4 + l4];
        uint4 r3 = HW4[(size_t)s3 * 4 + l4];
        uint4 r4 = HW4[(size_t)s4 * 4 + l4];
        uint4 r5 = HW4[(size_t)s5 * 4 + l4];
        uint4 r6 = HW4[(size_t)s6 * 4 + l4];
        uint4 r7 = HW4[(size_t)s7 * 4 + l4];
        float c0 = __int_as_float(q0.y) * did * ds0, c1 = __int_as_float(q0.w) * did * ds1;
        float c2 = __int_as_float(q1.y) * did * ds2, c3 = __int_as_float(q1.w) * did * ds3;
        float c4 = __int_as_float(q2.y) * did * ds4, c5 = __int_as_float(q2.w) * did * ds5;
        float c6 = __int_as_float(q3.y) * did * ds6, c7 = __int_as_float(q3.w) * did * ds7;
        ACC2(r0, c0) ACC2(r1, c1) ACC2(r2, c2) ACC2(r3, c3)
        ACC2(r4, c4) ACC2(r5, c5) ACC2(r6, c6) ACC2(r7, c7)
    }
    for (; e + 2 <= nc; e += 2) {
        int4 q = sp4[e >> 1];
        int s0 = q.x & SMASK, s1 = q.z & SMASK;
        float ds0 = dinv[s0], ds1 = dinv[s1];
        uint4 r0 = HW4[(size_t)s0 * 4 + l4];
        uint4 r1 = HW4[(size_t)s1 * 4 + l4];
        float c0 = __int_as_float(q.y) * did * ds0, c1 = __int_as_float(q.w) * did * ds1;
        ACC2(r0, c0) ACC2(r1, c1)
    }
    if (e < nc) {
        int2 p = sp[e];
        int s = p.x & SMASK;
        float c = __int_as_float(p.y) * did * dinv[s];
        uint4 r = HW4[(size_t)s * 4 + l4];
        ACC2(r, c)
    }
#undef ACC2
    float4* o4 = (float4*)out + (size_t)d * 8 + l4 * 2;
    o4[0] = make_float4(a0, a1, a2, a3);
    o4[1] = make_float4(a4, a5, a6, a7);
}

// ---------------- launch ----------------

extern "C" void kernel_launch(void* const* d_in, const int* in_sizes, int n_in,
                              void* d_out, int out_size, void* d_ws, size_t ws_size,
                              hipStream_t stream) {
    const float* x = (const float*)d_in[0];
    const int* edge_index = (const int*)d_in[1];
    const float* ew = (const float*)d_in[2];
    const float* W1 = (const float*)d_in[3];
    const float* b1 = (const float*)d_in[4];
    const float* W2 = (const float*)d_in[5];
    const float* b2 = (const float*)d_in[6];
    float* out = (float*)d_out;

    const int* src = edge_index;
    const int* dst = edge_index + N_EDGES;

    char* ws = (char*)d_ws;
    size_t off = 0;
    auto carve = [&](size_t bytes) -> void* {
        void* p = ws + off;
        off += (bytes + 255) & ~(size_t)255;
        return p;
    };

    int* gcnt = (int*)carve(NB * 4);
    float* dinv = (float*)carve((size_t)N_NODES * 4);
    int2* rowRC = (int2*)carve((size_t)N_NODES * 8);
    int2* seg = (int2*)carve((size_t)NB * SEG_CAP * 8);          // 15.2 MB
    int2* seg2 = (int2*)carve((size_t)NB * SEG_CAP * 8);         // 15.2 MB
    unsigned int* XWs = (unsigned int*)carve((size_t)N_NODES * 32 * 4);  // 12.8 MB bf16x2
    unsigned int* HWs = (unsigned int*)carve((size_t)N_NODES * 16 * 4);  // 6.4 MB bf16x2

    hipMemsetAsync(gcnt, 0, NB * 4, stream);
    fused1_kernel<<<BIN_BLOCKS + G1_BLOCKS, 512, 0, stream>>>(src, dst, ew, gcnt, seg,
                                                              x, W1, XWs);
    bsort_kernel<<<NB, 1024, 0, stream>>>(gcnt, seg, seg2, dinv, rowRC);
    agg1_kernel<<<N_NODES / 32, 256, 0, stream>>>(rowRC, seg2, XWs, dinv, b1, W2, HWs);
    agg2_kernel<<<(N_NODES + 63) / 64, 256, 0, stream>>>(rowRC, seg2, HWs, dinv, b2, out);
}

// Round 9
// 203.327 us; speedup vs baseline: 1.2198x; 1.0314x over previous
//
#include <hip/hip_runtime.h>

#define N_NODES 100000
#define N_EDGES 1600000
#define IN_C 64
#define HID_C 64
#define OUT_C 32

#define NB 391              // ceil(100000/256) dst buckets of 256 nodes
#define BSHIFT 8
#define BMASK 255
#define SEG_CAP 4864        // per-bucket capacity: mean 4096 + align pad + slack
#define EPB 6272            // 256 bin blocks (<=1 per CU) + 16-edge runs (R6)
#define BIN_BLOCKS ((N_EDGES + EPB - 1) / EPB)  // 256
#define G1_BLOCKS ((N_NODES + 63) / 64)         // 1563
#define SMASK 0x1FFFF       // 17-bit src field
#define FIXSCALE 34359738368.0f   // 2^35: count<<48 | sum(w)<<35 can't overflow

// bf16 pack/unpack (round-to-nearest-even)
__device__ __forceinline__ unsigned int bpack(float a, float b) {
    unsigned int ua = __float_as_uint(a);
    ua += 0x7FFFu + ((ua >> 16) & 1u);
    unsigned int ub = __float_as_uint(b);
    ub += 0x7FFFu + ((ub >> 16) & 1u);
    return (ua >> 16) | (ub & 0xFFFF0000u);
}
__device__ __forceinline__ float2 bup(unsigned int v) {
    return make_float2(__uint_as_float(v << 16), __uint_as_float(v & 0xFFFF0000u));
}

// ---------------- fused pass 1: bin (blocks 0..255) + gemm1 unscaled (rest) ----------------
// R2 lesson: bin MUST be co-resident with gemm1 (alone: VALUBusy 0.9%, 107 us)
// and runs must be long (short runs = +35 MB write amp). R8 lesson: 256-thread
// blocks with 32 KB union (4-5 co-resident gemm blocks) beat 512-thread/48 KB.

struct BinSh {
    int meta[EPB];      // 25.1 KB: rank within (block,bucket)
    int hist[NB];       // 1.6 KB
    int gbase[NB];      // 1.6 KB
};
struct G1Sh {
    float XsT[64][64];  // 16 KB
    float Ws[64][64];   // 16 KB
};
union FusedSh { BinSh b; G1Sh g; };  // 32 KB

__global__ void __launch_bounds__(256) fused1_kernel(
    const int* __restrict__ src, const int* __restrict__ dst,
    const float* __restrict__ w, int* __restrict__ gcnt, int2* __restrict__ seg,
    const float* __restrict__ X, const float* __restrict__ W,
    unsigned int* __restrict__ XWu) {
    __shared__ FusedSh sh;
    int tid = threadIdx.x;
    if (blockIdx.x < BIN_BLOCKS) {
        // ---- bin body ----
        for (int i = tid; i < NB; i += 256) sh.b.hist[i] = 0;
        __syncthreads();
        int e0 = blockIdx.x * EPB;
        int n = min(EPB, N_EDGES - e0);   // multiple of 4 (tail block = 640)
        const int4* dst4 = (const int4*)(dst + e0);
        int n4 = n >> 2;
        // phase 1: count + rank.  meta slot transposed (K*n4+i): stride-1 per lane.
        for (int i = tid; i < n4; i += 256) {
            int4 d = dst4[i];
            int b0 = d.x >> BSHIFT, b1 = d.y >> BSHIFT;
            int b2 = d.z >> BSHIFT, b3 = d.w >> BSHIFT;
            sh.b.meta[0 * n4 + i] = atomicAdd(&sh.b.hist[b0], 1);
            sh.b.meta[1 * n4 + i] = atomicAdd(&sh.b.hist[b1], 1);
            sh.b.meta[2 * n4 + i] = atomicAdd(&sh.b.hist[b2], 1);
            sh.b.meta[3 * n4 + i] = atomicAdd(&sh.b.hist[b3], 1);
        }
        __syncthreads();
        for (int b = tid; b < NB; b += 256) {
            int c = sh.b.hist[b];
            sh.b.gbase[b] = c ? atomicAdd(&gcnt[b], c) : 0;
        }
        __syncthreads();
        // phase 2: re-read edges (L2-hot), recompute record, scatter in runs.
        const int4* src4 = (const int4*)(src + e0);
        const float4* w4 = (const float4*)(w + e0);
        for (int i = tid; i < n4; i += 256) {
            int4 s = src4[i];
            int4 d = dst4[i];
            float4 ww = w4[i];
#define FL_ONE(K, SS, DD, WW)                                              \
            {                                                              \
                int b = (DD) >> BSHIFT;                                    \
                int pos = sh.b.gbase[b] + sh.b.meta[K * n4 + i];           \
                if (pos < SEG_CAP)                                         \
                    seg[(size_t)b * SEG_CAP + pos] =                       \
                        make_int2((SS) | (((DD) & BMASK) << 17),           \
                                  __float_as_int(WW));                     \
            }
            FL_ONE(0, s.x, d.x, ww.x)
            FL_ONE(1, s.y, d.y, ww.y)
            FL_ONE(2, s.z, d.z, ww.z)
            FL_ONE(3, s.w, d.w, ww.w)
#undef FL_ONE
        }
    } else {
        // ---- gemm1 body: XWu = bf16(X @ W1), unscaled ----
        {
            const float4* Wv = (const float4*)W;
            float4* Wsv = (float4*)&sh.g.Ws[0][0];
            for (int i = tid; i < 1024; i += 256) Wsv[i] = Wv[i];
        }
        int row0 = (blockIdx.x - BIN_BLOCKS) * 64;
        int rmax = N_NODES - row0;
        for (int i = tid; i < 64 * 16; i += 256) {
            int r = i & 63, kq = i >> 6;  // consecutive lanes -> consecutive rows (conflict-free)
            float4 v = (r < rmax) ? ((const float4*)(X + (size_t)(row0 + r) * IN_C))[kq]
                                  : make_float4(0.f, 0.f, 0.f, 0.f);
            sh.g.XsT[4 * kq + 0][r] = v.x;
            sh.g.XsT[4 * kq + 1][r] = v.y;
            sh.g.XsT[4 * kq + 2][r] = v.z;
            sh.g.XsT[4 * kq + 3][r] = v.w;
        }
        __syncthreads();
        int tr = tid >> 4, tc = tid & 15;
        float acc[4][4] = {};
        float a[4], bb[4];
#pragma unroll 8
        for (int k = 0; k < 64; ++k) {
            *(float4*)a = *(const float4*)&sh.g.XsT[k][4 * tr];
            *(float4*)bb = *(const float4*)&sh.g.Ws[k][4 * tc];
#pragma unroll
            for (int i = 0; i < 4; ++i)
#pragma unroll
                for (int j = 0; j < 4; ++j) acc[i][j] += a[i] * bb[j];
        }
#pragma unroll
        for (int i = 0; i < 4; ++i) {
            int rl = 4 * tr + i;
            if (rl < rmax) {
                int row = row0 + rl;
                uint2 o;
                o.x = bpack(acc[i][0], acc[i][1]);
                o.y = bpack(acc[i][2], acc[i][3]);
                ((uint2*)XWu)[(size_t)row * 16 + tc] = o;
            }
        }
    }
}

// ---------------- pass 2: per-bucket counting sort -> runs + dinv (R6 form) ----------------
// The 25.6 MB XWs-RMW scale tail is gone (dinv[s] folded per-edge in agg).

__global__ void __launch_bounds__(1024) bsort_kernel(const int* __restrict__ gcnt,
                                                     const int2* __restrict__ seg,
                                                     int2* __restrict__ seg2,
                                                     float* __restrict__ dinv,
                                                     int2* __restrict__ rowRC) {
    __shared__ unsigned long long packed[256];   // 2 KB
    __shared__ int meta[SEG_CAP];                // 19 KB: dl | rank<<8
    __shared__ int sarr[256];
    __shared__ int ofs0[256];
    int tid = threadIdx.x, b = blockIdx.x;
    int n = min(gcnt[b], SEG_CAP);
    const int2* sp = seg + (size_t)b * SEG_CAP;
    if (tid < 256) packed[tid] = 0ULL;
    __syncthreads();
    for (int i = tid; i < n; i += 1024) {
        int2 r = sp[i];
        int dl = (r.x >> 17) & BMASK;
        unsigned long long fixw =
            (unsigned long long)(__int_as_float(r.y) * FIXSCALE);
        unsigned long long old = atomicAdd(&packed[dl], (1ULL << 48) | fixw);
        meta[i] = dl | ((int)(old >> 48) << 8);
    }
    __syncthreads();
    int myc = 0, padc = 0;
    if (tid < 256) {
        unsigned long long p = packed[tid];
        myc = (int)(p >> 48);
        float degw = (float)((double)(p & ((1ULL << 48) - 1)) * (1.0 / (double)FIXSCALE));
        float dv = rsqrtf(1.0f + degw);  // self-loop w=1
        int node = (b << BSHIFT) + tid;
        if (node < N_NODES) dinv[node] = dv;
        padc = (myc + 1) & ~1;  // even-align runs for int4 loads
        sarr[tid] = padc;
    }
    __syncthreads();
    for (int off = 1; off < 256; off <<= 1) {
        int tmp = 0;
        if (tid < 256 && tid >= off) tmp = sarr[tid - off];
        __syncthreads();
        if (tid < 256) sarr[tid] += tmp;
        __syncthreads();
    }
    if (tid < 256) {
        int excl = sarr[tid] - padc;
        int node = (b << BSHIFT) + tid;
        if (node < N_NODES) rowRC[node] = make_int2(b * SEG_CAP + excl, myc);
        ofs0[tid] = excl;
    }
    __syncthreads();
    int2* op = seg2 + (size_t)b * SEG_CAP;
    for (int i = tid; i < n; i += 1024) {
        int2 r = sp[i];                       // re-read, L2-hot
        int m = meta[i];
        int dl = m & BMASK, rank = m >> 8;
        op[ofs0[dl] + rank] = r;
    }
}

// ---------------- agg layer 1 + GEMM2 fused (R6-proven form) ----------------
// XWs unscaled; per-edge coefficient = w * dinv[d] * dinv[s] (dinv is a
// broadcast 4-B load from the L2-resident 400 KB table); self-term dinv[d]^2.
// 8 nodes/wave x 8 lanes/node, uint4/lane. FETCH ~99 MB = compulsory floor
// (8 XCDs x 12.8 MB table) at ~2.4 TB/s random-line service.

__global__ void __launch_bounds__(256) agg1_kernel(const int2* __restrict__ rowRC,
                                                   const int2* __restrict__ seg2,
                                                   const unsigned int* __restrict__ XWs,
                                                   const float* __restrict__ dinv,
                                                   const float* __restrict__ b1,
                                                   const float* __restrict__ W2,
                                                   unsigned int* __restrict__ HWs) {
    __shared__ float Hs[32][68];    // 8.5 KB (+4 pad)
    __shared__ float Ws2[64][32];   // 8 KB
    int tid = threadIdx.x;
    {   // stage W2 while gathers are in flight
        const float4* Wv = (const float4*)W2;
        float4* Wsv = (float4*)&Ws2[0][0];
        for (int i = tid; i < 512; i += 256) Wsv[i] = Wv[i];
    }
    int l8 = tid & 7;                        // channel-octet lane 0..7
    int nl = tid >> 3;                       // node-local 0..31
    int d = blockIdx.x * 32 + nl;            // always < N_NODES (3125*32)
    const uint4* XW4 = (const uint4*)XWs;    // row = 8 uint4 (128 B)
    float did = dinv[d];
    float selfc = did * did;                 // self-loop: dinv[d] * 1 * dinv[d]
    float4 bv0 = ((const float4*)b1)[2 * l8];
    float4 bv1 = ((const float4*)b1)[2 * l8 + 1];
    uint4 sv = XW4[(size_t)d * 8 + l8];
    float2 v;
    float a0, a1, a2, a3, a4, a5, a6, a7;
    v = bup(sv.x); a0 = bv0.x + selfc * v.x; a1 = bv0.y + selfc * v.y;
    v = bup(sv.y); a2 = bv0.z + selfc * v.x; a3 = bv0.w + selfc * v.y;
    v = bup(sv.z); a4 = bv1.x + selfc * v.x; a5 = bv1.y + selfc * v.y;
    v = bup(sv.w); a6 = bv1.z + selfc * v.x; a7 = bv1.w + selfc * v.y;
    int2 rc = rowRC[d];
    int nc = rc.y;
    const int2* sp = seg2 + rc.x;
    const int4* sp4 = (const int4*)sp;
    int e = 0;
#define ACC1(R, C)                                                         \
    v = bup(R.x); a0 += (C) * v.x; a1 += (C) * v.y;                        \
    v = bup(R.y); a2 += (C) * v.x; a3 += (C) * v.y;                        \
    v = bup(R.z); a4 += (C) * v.x; a5 += (C) * v.y;                        \
    v = bup(R.w); a6 += (C) * v.x; a7 += (C) * v.y;
    for (; e + 8 <= nc; e += 8) {
        int4 q0 = sp4[(e >> 1) + 0], q1 = sp4[(e >> 1) + 1];
        int4 q2 = sp4[(e >> 1) + 2], q3 = sp4[(e >> 1) + 3];
        int s0 = q0.x & SMASK, s1 = q0.z & SMASK, s2 = q1.x & SMASK, s3 = q1.z & SMASK;
        int s4 = q2.x & SMASK, s5 = q2.z & SMASK, s6 = q3.x & SMASK, s7 = q3.z & SMASK;
        float ds0 = dinv[s0], ds1 = dinv[s1], ds2 = dinv[s2], ds3 = dinv[s3];
        float ds4 = dinv[s4], ds5 = dinv[s5], ds6 = dinv[s6], ds7 = dinv[s7];
        uint4 r0 = XW4[(size_t)s0 * 8 + l8];
        uint4 r1 = XW4[(size_t)s1 * 8 + l8];
        uint4 r2 = XW4[(size_t)s2 * 8 + l8];
        uint4 r3 = XW4[(size_t)s3 * 8 + l8];
        uint4 r4 = XW4[(size_t)s4 * 8 + l8];
        uint4 r5 = XW4[(size_t)s5 * 8 + l8];
        uint4 r6 = XW4[(size_t)s6 * 8 + l8];
        uint4 r7 = XW4[(size_t)s7 * 8 + l8];
        float c0 = __int_as_float(q0.y) * did * ds0, c1 = __int_as_float(q0.w) * did * ds1;
        float c2 = __int_as_float(q1.y) * did * ds2, c3 = __int_as_float(q1.w) * did * ds3;
        float c4 = __int_as_float(q2.y) * did * ds4, c5 = __int_as_float(q2.w) * did * ds5;
        float c6 = __int_as_float(q3.y) * did * ds6, c7 = __int_as_float(q3.w) * did * ds7;
        ACC1(r0, c0) ACC1(r1, c1) ACC1(r2, c2) ACC1(r3, c3)
        ACC1(r4, c4) ACC1(r5, c5) ACC1(r6, c6) ACC1(r7, c7)
    }
    for (; e + 2 <= nc; e += 2) {
        int4 q = sp4[e >> 1];
        int s0 = q.x & SMASK, s1 = q.z & SMASK;
        float ds0 = dinv[s0], ds1 = dinv[s1];
        uint4 r0 = XW4[(size_t)s0 * 8 + l8];
        uint4 r1 = XW4[(size_t)s1 * 8 + l8];
        float c0 = __int_as_float(q.y) * did * ds0, c1 = __int_as_float(q.w) * did * ds1;
        ACC1(r0, c0) ACC1(r1, c1)
    }
    if (e < nc) {
        int2 p = sp[e];
        int s = p.x & SMASK;
        float c = __int_as_float(p.y) * did * dinv[s];
        uint4 r = XW4[(size_t)s * 8 + l8];
        ACC1(r, c)
    }
#undef ACC1
    // ---- ReLU + stage H tile (thread (nl,l8) holds ch 8*l8..8*l8+7 of node nl) ----
    *(float4*)&Hs[nl][8 * l8] = make_float4(fmaxf(a0, 0.f), fmaxf(a1, 0.f),
                                            fmaxf(a2, 0.f), fmaxf(a3, 0.f));
    *(float4*)&Hs[nl][8 * l8 + 4] = make_float4(fmaxf(a4, 0.f), fmaxf(a5, 0.f),
                                                fmaxf(a6, 0.f), fmaxf(a7, 0.f));
    __syncthreads();
    // ---- 32x64 @ 64x32 epilogue: HWs = bf16(H @ W2), UNSCALED (agg2 applies dinv) ----
    int nl2 = tid >> 3, cg = tid & 7;
    int d2 = blockIdx.x * 32 + nl2;
    float o0 = 0.f, o1 = 0.f, o2 = 0.f, o3 = 0.f;
#pragma unroll
    for (int k = 0; k < 64; ++k) {
        float hk = Hs[nl2][k];                      // broadcast within 8-lane group
        float4 wv = *(const float4*)&Ws2[k][4 * cg];
        o0 += hk * wv.x; o1 += hk * wv.y; o2 += hk * wv.z; o3 += hk * wv.w;
    }
    uint2 o;
    o.x = bpack(o0, o1);
    o.y = bpack(o2, o3);
    ((uint2*)HWs)[(size_t)d2 * 8 + cg] = o;   // row = 8 uint2 (64 B)
}

// ---------------- agg layer 2: 16 nodes/wave, uint4/lane, dinv[s] per edge (R6 form) ------

__global__ void __launch_bounds__(256) agg2_kernel(const int2* __restrict__ rowRC,
                                                   const int2* __restrict__ seg2,
                                                   const unsigned int* __restrict__ HWs,
                                                   const float* __restrict__ dinv,
                                                   const float* __restrict__ b2,
                                                   float* __restrict__ out) {
    int l4 = threadIdx.x & 3;                // channel-octet lane 0..3
    int d = blockIdx.x * 64 + (threadIdx.x >> 2);
    if (d >= N_NODES) return;
    const uint4* HW4 = (const uint4*)HWs;    // row = 4 uint4 (64 B)
    float did = dinv[d];
    float selfc = did * did;
    float4 bv0 = ((const float4*)b2)[2 * l4];
    float4 bv1 = ((const float4*)b2)[2 * l4 + 1];
    uint4 sv = HW4[(size_t)d * 4 + l4];
    float2 v;
    float a0, a1, a2, a3, a4, a5, a6, a7;
    v = bup(sv.x); a0 = bv0.x + selfc * v.x; a1 = bv0.y + selfc * v.y;
    v = bup(sv.y); a2 = bv0.z + selfc * v.x; a3 = bv0.w + selfc * v.y;
    v = bup(sv.z); a4 = bv1.x + selfc * v.x; a5 = bv1.y + selfc * v.y;
    v = bup(sv.w); a6 = bv1.z + selfc * v.x; a7 = bv1.w + selfc * v.y;
    int2 rc = rowRC[d];
    int nc = rc.y;
    const int2* sp = seg2 + rc.x;
    const int4* sp4 = (const int4*)sp;
    int e = 0;
#define ACC2(R, C)                                                         \
    v = bup(R.x); a0 += (C) * v.x; a1 += (C) * v.y;                        \
    v = bup(R.y); a2 += (C) * v.x; a3 += (C) * v.y;                        \
    v = bup(R.z); a4 += (C) * v.x; a5 += (C) * v.y;                        \
    v = bup(R.w); a6 += (C) * v.x; a7 += (C) * v.y;
    for (; e + 8 <= nc; e += 8) {
        int4 q0 = sp4[(e >> 1) + 0], q1 = sp4[(e >> 1) + 1];
        int4 q2 = sp4[(e >> 1) + 2], q3 = sp4[(e >> 1) + 3];
        int s0 = q0.x & SMASK, s1 = q0.z & SMASK, s2 = q1.x & SMASK, s3 = q1.z & SMASK;
        int s4 = q2.x & SMASK, s5 = q2.z & SMASK, s6 = q3.x & SMASK, s7 = q3.z & SMASK;
        float ds0 = dinv[s0], ds1 = dinv[s1], ds2 = dinv[s2], ds3 = dinv[s3];
        float ds4 = dinv[s4], ds5 = dinv[s5], ds6 = dinv[s6], ds7 = dinv[s7];
        uint4 r0 = HW4[(size_t)s0 * 4 + l4];
        uint4 r1 = HW4[(size_t)s1 * 4 + l4];
        uint4 r2 = HW4[(size_t)s2 * 4 + l4];
        uint4 r3 = HW4[(size_t)s3 * 4 + l4];
        uint4 r4 = HW4[(size_t)s4 * 4 + l4];
        uint4 r5 = HW4[(size_t)s5 * 4 + l4];
        uint4 r6 = HW4[(size_t)s6 * 4 + l4];
        uint4 r7 = HW4[(size_t)s7 * 4 + l4];
        float c0 = __int_as_float(q0.y) * did * ds0, c1 = __int_as_float(q0.w) * did * ds1;
        float c2 = __int_as_float(q1.y) * did * ds2, c3 = __int_as_float(q1.w) * did * ds3;
        float c4 = __int_as_float(q2.y) * did * ds4, c5 = __int_as_float(q2.w) * did * ds5;
        float c6 = __int_as_float(q3.y) * did * ds6, c7 = __int_as_float(q3.w) * did * ds7;
        ACC2(r0, c0) ACC2(r1, c1) ACC2(r2, c2) ACC2(r3, c3)
        ACC2(r4, c4) ACC2(r5, c5) ACC2(r6, c6) ACC2(r7, c7)
    }
    for (; e + 2 <= nc; e += 2) {
        int4 q = sp4[e >> 1];
        int s0 = q.x & SMASK, s1 = q.z & SMASK;
        float ds0 = dinv[s0], ds1 = dinv[s1];
        uint4 r0 = HW4[(size_t)s0 * 4 + l4];
        uint4 r1 = HW4[(size_t)s1 * 4 + l4];
        float c0 = __int_as_float(q.y) * did * ds0, c1 = __int_as_float(q.w) * did * ds1;
        ACC2(r0, c0) ACC2(r1, c1)
    }
    if (e < nc) {
        int2 p = sp[e];
        int s = p.x & SMASK;
        float c = __int_as_float(p.y) * did * dinv[s];
        uint4 r = HW4[(size_t)s * 4 + l4];
        ACC2(r, c)
    }
#undef ACC2
    float4* o4 = (float4*)out + (size_t)d * 8 + l4 * 2;
    o4[0] = make_float4(a0, a1, a2, a3);
    o4[1] = make_float4(a4, a5, a6, a7);
}

// ---------------- launch ----------------

extern "C" void kernel_launch(void* const* d_in, const int* in_sizes, int n_in,
                              void* d_out, int out_size, void* d_ws, size_t ws_size,
                              hipStream_t stream) {
    const float* x = (const float*)d_in[0];
    const int* edge_index = (const int*)d_in[1];
    const float* ew = (const float*)d_in[2];
    const float* W1 = (const float*)d_in[3];
    const float* b1 = (const float*)d_in[4];
    const float* W2 = (const float*)d_in[5];
    const float* b2 = (const float*)d_in[6];
    float* out = (float*)d_out;

    const int* src = edge_index;
    const int* dst = edge_index + N_EDGES;

    char* ws = (char*)d_ws;
    size_t off = 0;
    auto carve = [&](size_t bytes) -> void* {
        void* p = ws + off;
        off += (bytes + 255) & ~(size_t)255;
        return p;
    };

    int* gcnt = (int*)carve(NB * 4);
    float* dinv = (float*)carve((size_t)N_NODES * 4);
    int2* rowRC = (int2*)carve((size_t)N_NODES * 8);
    int2* seg = (int2*)carve((size_t)NB * SEG_CAP * 8);          // 15.2 MB
    int2* seg2 = (int2*)carve((size_t)NB * SEG_CAP * 8);         // 15.2 MB
    unsigned int* XWs = (unsigned int*)carve((size_t)N_NODES * 32 * 4);  // 12.8 MB bf16x2
    unsigned int* HWs = (unsigned int*)carve((size_t)N_NODES * 16 * 4);  // 6.4 MB bf16x2

    hipMemsetAsync(gcnt, 0, NB * 4, stream);
    fused1_kernel<<<BIN_BLOCKS + G1_BLOCKS, 256, 0, stream>>>(src, dst, ew, gcnt, seg,
                                                              x, W1, XWs);
    bsort_kernel<<<NB, 1024, 0, stream>>>(gcnt, seg, seg2, dinv, rowRC);
    agg1_kernel<<<N_NODES / 32, 256, 0, stream>>>(rowRC, seg2, XWs, dinv, b1, W2, HWs);
    agg2_kernel<<<(N_NODES + 63) / 64, 256, 0, stream>>>(rowRC, seg2, HWs, dinv, b2, out);
}